// Round 11
// baseline (296.323 us; speedup 1.0000x reference)
//
#include <hip/hip_runtime.h>
#include <hip/hip_bf16.h>

typedef __attribute__((ext_vector_type(8))) short s16x8;
typedef __attribute__((ext_vector_type(4))) float f32x4;
typedef unsigned short u16;
typedef unsigned int u32;

constexpr int NN = 50000;
constexpr int NE = 600000;

__device__ inline u16 f2b(float x) {
    __hip_bfloat16 h = __float2bfloat16(x);
    return *(u16*)&h;
}

__device__ inline s16x8 pack8(float4 a, float4 b) {
    s16x8 r;
    r[0] = (short)f2b(a.x); r[1] = (short)f2b(a.y);
    r[2] = (short)f2b(a.z); r[3] = (short)f2b(a.w);
    r[4] = (short)f2b(b.x); r[5] = (short)f2b(b.y);
    r[6] = (short)f2b(b.z); r[7] = (short)f2b(b.w);
    return r;
}

// async global->LDS DMA, 16B per lane: LDS dst = wave-uniform base + lane*16.
__device__ inline void gl_lds16(const void* gptr, void* lptr) {
    __builtin_amdgcn_global_load_lds(
        (const __attribute__((address_space(1))) char*)gptr,
        (__attribute__((address_space(3))) char*)lptr, 16, 0, 0);
}

template <int N> __device__ inline void vmwait() {
    asm volatile("s_waitcnt vmcnt(%0)" :: "n"(N) : "memory");
}
__device__ inline void barrier_nodrains() {
    __builtin_amdgcn_sched_barrier(0);
    __builtin_amdgcn_s_barrier();
    __builtin_amdgcn_sched_barrier(0);
}

// ---------------- misc small kernels ----------------

__global__ void k_zero(int* __restrict__ p, int n) {
    int i = blockIdx.x * 256 + threadIdx.x;
    if (i < n) p[i] = 0;
}

__global__ void k_padvf(const float* __restrict__ vf, float* __restrict__ vp) {
    int i = blockIdx.x * 256 + threadIdx.x;
    if (i < NN * 32) {
        int n = i >> 5, c = i & 31;
        vp[i] = c < 16 ? vf[n * 16 + c] : 0.f;
    }
}

// WTin[c][k], k<768: (fc2_w @ relu_w_bot)^T ; 768..783: (fc1_w @ relu_w_top)^T ; 784..799: 0
__global__ void k_win(const float* __restrict__ fc1w, const float* __restrict__ fc2w,
                      const float* __restrict__ reluw, u16* __restrict__ WTin) {
    int c = threadIdx.x;
    int k = blockIdx.x;
    float s = 0.f;
    if (k < 768) {
        for (int j = 0; j < 128; ++j) s += fc2w[k * 128 + j] * reluw[(128 + j) * 128 + c];
    } else if (k < 784) {
        int kk = k - 768;
        for (int j = 0; j < 128; ++j) s += fc1w[kk * 128 + j] * reluw[j * 128 + c];
    }
    WTin[c * 800 + k] = f2b(s);
}

__global__ void k_bcomb(const float* __restrict__ fc1b, const float* __restrict__ fc2b,
                        const float* __restrict__ relub, const float* __restrict__ reluw,
                        float* __restrict__ bcomb) {
    int c = threadIdx.x;
    float s = relub[c];
    for (int j = 0; j < 128; ++j) {
        s += fc1b[j] * reluw[j * 128 + c];
        s += fc2b[j] * reluw[(128 + j) * 128 + c];
    }
    bcomb[c] = s;
}

// WT[c][s] = stacked [wrel(3x128x128); wroot(128x128)] transposed, bf16
__global__ void k_wrg(const float* __restrict__ wrel, const float* __restrict__ wroot,
                      u16* __restrict__ WT) {
    int c = threadIdx.x;
    int s = blockIdx.x;
    float v = (s < 384) ? wrel[(size_t)s * 128 + c] : wroot[(size_t)(s - 384) * 128 + c];
    WT[c * 512 + s] = f2b(v);
}

// ---------------- CSR build ----------------

__global__ void k_hist(const int* __restrict__ ei, const int* __restrict__ et,
                       int* __restrict__ deg_node, int* __restrict__ deg_rel) {
    int e = blockIdx.x * 256 + threadIdx.x;
    if (e >= NE) return;
    int dst = ei[NE + e];
    int r = et[e];
    atomicAdd(&deg_node[dst], 1);
    atomicAdd(&deg_rel[r * NN + dst], 1);
}

__global__ void k_alloc(const int* __restrict__ deg_node, int* __restrict__ baseoff,
                        int* __restrict__ counter) {
    int i = blockIdx.x * 256 + threadIdx.x;
    int lane = threadIdx.x & 63;
    int d = (i < NN) ? deg_node[i] : 0;
    int scan = d;
    for (int off = 1; off < 64; off <<= 1) {
        int t = __shfl_up(scan, off, 64);
        if (lane >= off) scan += t;
    }
    int total = __shfl(scan, 63, 64);
    int wbase = 0;
    if (lane == 63) wbase = atomicAdd(counter, total);
    wbase = __shfl(wbase, 63, 64);
    if (i < NN) baseoff[i] = wbase + scan - d;
}

__global__ void k_norm(const int* __restrict__ deg_rel, float* __restrict__ normf) {
    int i = blockIdx.x * 256 + threadIdx.x;
    if (i < 3 * NN) normf[i] = 1.0f / (float)max(deg_rel[i], 1);
}

__global__ void k_fill(const int* __restrict__ ei, const int* __restrict__ et,
                       const int* __restrict__ baseoff, int* __restrict__ cursor,
                       int* __restrict__ elist) {
    int e = blockIdx.x * 256 + threadIdx.x;
    if (e >= NE) return;
    int dst = ei[NE + e];
    int src = ei[e];
    int r = et[e];
    int pos = atomicAdd(&cursor[dst], 1);
    elist[baseoff[dst] + pos] = src | (r << 20);
}

// ---------------- aggregation (gather over CSR): 1 wave per node ----------------

__global__ __launch_bounds__(64) void k_agg(const u16* __restrict__ x, u16* __restrict__ A,
                                            const int* __restrict__ elist,
                                            const int* __restrict__ baseoff,
                                            const int* __restrict__ deg_node,
                                            const float* __restrict__ normf) {
    int n = blockIdx.x;
    int lane = threadIdx.x;
    float a0x = 0.f, a0y = 0.f, a1x = 0.f, a1y = 0.f, a2x = 0.f, a2y = 0.f;
    int nb = deg_node[n];
    int b0 = baseoff[n];
    for (int i = 0; i < nb; ++i) {
        int p = elist[b0 + i];
        int src = p & 0xFFFFF;
        int r = p >> 20;
        u32 pair = *(const u32*)&x[(size_t)src * 128 + lane * 2];
        float vx = __uint_as_float((pair & 0xFFFFu) << 16);
        float vy = __uint_as_float((pair >> 16) << 16);
        if (r == 0)      { a0x += vx; a0y += vy; }
        else if (r == 1) { a1x += vx; a1y += vy; }
        else             { a2x += vx; a2y += vy; }
    }
    float n0 = normf[n], n1 = normf[NN + n], n2 = normf[2 * NN + n];
    u32* Ao = (u32*)&A[(size_t)n * 384];
    Ao[lane]        = (u32)f2b(a0x * n0) | ((u32)f2b(a0y * n0) << 16);
    Ao[64 + lane]   = (u32)f2b(a1x * n1) | ((u32)f2b(a1y * n1) << 16);
    Ao[128 + lane]  = (u32)f2b(a2x * n2) | ((u32)f2b(a2y * n2) << 16);
}

// ---------------- GEMM body: [N, 32*(K1T+K2T)] x WT^T -> [N,128] bf16 ----------------
// BM=64 (4 waves in 2x2, wave tile 32x64, 8 MFMA/k-step) x round-9 pipeline:
// 3 LDS buffers, prefetch depth 2, counted vmcnt(OPW) at the barrier. LDS 36KB
// (bf16) / 48KB (fp32) -> 4 / 3 blocks per CU; grid 782 -> ~3 blocks/CU
// co-resident so other blocks' waves fill each block's per-k-step latency.

template <typename TA, int K1T, int K2T, bool LRELU>
__device__ __forceinline__ void gemm_body(const TA* __restrict__ A1, int lda1,
                                          const TA* __restrict__ A2, int lda2,
                                          const u16* __restrict__ WT, int ldwt,
                                          const float* __restrict__ bias,
                                          u16* __restrict__ out, int N) {
    constexpr int KT = K1T + K2T;
    constexpr int ABYTES = 64 * 32 * (int)sizeof(TA);
    constexpr int TILEB = ABYTES + 8192;
    constexpr int OPW = (sizeof(TA) == 4) ? 4 : 3;   // DMA instrs per wave per stage
    __shared__ alignas(128) char lds[3][TILEB];

    const int tid = threadIdx.x;
    const int m0 = blockIdx.x * 64;
    const int w = tid >> 6, lane = tid & 63;
    const int wr = w >> 1, wc = w & 1;
    const int lq = lane >> 4, lr = lane & 15;

    auto stage = [&](int j) {
        char* base = lds[j % 3];
        int kt = j;
        // ---- A tile [64 rows][32 cols] ----
        if constexpr (sizeof(TA) == 4) {
#pragma unroll
            for (int jj = 0; jj < 2; ++jj) {
                int row = w * 16 + jj * 8 + (lane >> 3);
                int s = lane & 7;
                int chunk = s ^ (row & 7);
                int rg = min(m0 + row, N - 1);
                const float* g;
                if (kt < K1T) g = (const float*)A1 + (size_t)rg * lda1 + kt * 32 + chunk * 4;
                else          g = (const float*)A2 + (size_t)rg * lda2 + (kt - K1T) * 32 + chunk * 4;
                gl_lds16(g, base + w * 2048 + jj * 1024);
            }
        } else {
            int row = w * 16 + (lane >> 2);
            int s = lane & 3;
            int chunk = s ^ ((row >> 1) & 3);
            int rg = min(m0 + row, N - 1);
            const u16* g;
            if (kt < K1T) g = (const u16*)A1 + (size_t)rg * lda1 + kt * 32 + chunk * 8;
            else          g = (const u16*)A2 + (size_t)rg * lda2 + (kt - K1T) * 32 + chunk * 8;
            gl_lds16(g, base + w * 1024);
        }
        // ---- B tile [128 cols][32 k] ----
#pragma unroll
        for (int jj = 0; jj < 2; ++jj) {
            int col = w * 32 + jj * 16 + (lane >> 2);
            int s = lane & 3;
            int chunk = s ^ ((col >> 1) & 3);
            const u16* g = WT + (size_t)col * ldwt + kt * 32 + chunk * 8;
            gl_lds16(g, base + ABYTES + w * 2048 + jj * 1024);
        }
    };

    f32x4 acc[2][4] = {};

    auto compute = [&](int j) {
        char* base = lds[j % 3];
        s16x8 af[2];
#pragma unroll
        for (int i = 0; i < 2; ++i) {
            int row = wr * 32 + i * 16 + lr;
            if constexpr (sizeof(TA) == 4) {
                int m = row & 7;
                float4 f0 = *(const float4*)(base + row * 128 + (((2 * lq) ^ m) * 16));
                float4 f1 = *(const float4*)(base + row * 128 + (((2 * lq + 1) ^ m) * 16));
                af[i] = pack8(f0, f1);
            } else {
                int sl = lq ^ ((row >> 1) & 3);
                af[i] = *(const s16x8*)(base + row * 64 + sl * 16);
            }
        }
#pragma unroll
        for (int j4 = 0; j4 < 4; ++j4) {
            int col = wc * 64 + j4 * 16 + lr;
            int sl = lq ^ ((col >> 1) & 3);
            s16x8 bf = *(const s16x8*)(base + ABYTES + col * 64 + sl * 16);
#pragma unroll
            for (int i = 0; i < 2; ++i)
                acc[i][j4] = __builtin_amdgcn_mfma_f32_16x16x32_bf16(af[i], bf, acc[i][j4], 0, 0, 0);
        }
    };

    stage(0); stage(1);
#pragma unroll 1
    for (int j = 0; j < KT - 1; ++j) {
        vmwait<OPW>();             // stage(j) landed; stage(j+1) stays in flight
        barrier_nodrains();
        if (j + 2 < KT) stage(j + 2);
        compute(j);
    }
    vmwait<0>();
    barrier_nodrains();
    compute(KT - 1);

#pragma unroll
    for (int i = 0; i < 2; ++i) {
#pragma unroll
        for (int q = 0; q < 4; ++q) {
            int grow = m0 + wr * 32 + i * 16 + lq * 4 + q;
            if (grow < N) {
#pragma unroll
                for (int j = 0; j < 4; ++j) {
                    int col = wc * 64 + j * 16 + lr;
                    float v = acc[i][j][q] + bias[col];
                    if (LRELU) v = v > 0.f ? v : 0.01f * v;
                    out[(size_t)grow * 128 + col] = f2b(v);
                }
            }
        }
    }
}

// distinct names for profile attribution
__global__ __launch_bounds__(256) void k_gemm_in(const float* __restrict__ A1, int lda1,
                                                 const float* __restrict__ A2, int lda2,
                                                 const u16* __restrict__ WT, int ldwt,
                                                 const float* __restrict__ bias,
                                                 u16* __restrict__ out, int N) {
    gemm_body<float, 24, 1, true>(A1, lda1, A2, lda2, WT, ldwt, bias, out, N);
}
__global__ __launch_bounds__(256) void k_gemm_r1(const u16* __restrict__ A1, int lda1,
                                                 const u16* __restrict__ A2, int lda2,
                                                 const u16* __restrict__ WT, int ldwt,
                                                 const float* __restrict__ bias,
                                                 u16* __restrict__ out, int N) {
    gemm_body<u16, 12, 4, false>(A1, lda1, A2, lda2, WT, ldwt, bias, out, N);
}
__global__ __launch_bounds__(256) void k_gemm_r2(const u16* __restrict__ A1, int lda1,
                                                 const u16* __restrict__ A2, int lda2,
                                                 const u16* __restrict__ WT, int ldwt,
                                                 const float* __restrict__ bias,
                                                 u16* __restrict__ out, int N) {
    gemm_body<u16, 12, 4, false>(A1, lda1, A2, lda2, WT, ldwt, bias, out, N);
}

// ---------------- final gather + classifier ----------------

__global__ __launch_bounds__(256) void k_out(const u16* __restrict__ h, const int* __restrict__ idx,
                                             const float* __restrict__ fc3w,
                                             const float* __restrict__ fc3b,
                                             float* __restrict__ out, int M) {
    int w = threadIdx.x >> 6;
    int lane = threadIdx.x & 63;
    int row = blockIdx.x * 4 + w;
    if (row >= M) return;
    int n = idx[row];
    u32 pair = *(const u32*)&h[(size_t)n * 128 + lane * 2];
    float v0 = __uint_as_float((pair & 0xFFFFu) << 16);
    float v1 = __uint_as_float((pair >> 16) << 16);
    float4 wv = *(const float4*)&fc3w[lane * 4];
    float s0 = v0 * wv.x + v1 * wv.z;
    float s1 = v0 * wv.y + v1 * wv.w;
    for (int off = 32; off >= 1; off >>= 1) {
        s0 += __shfl_xor(s0, off, 64);
        s1 += __shfl_xor(s1, off, 64);
    }
    if (lane == 0) {
        out[row * 2] = s0 + fc3b[0];
        out[row * 2 + 1] = s1 + fc3b[1];
    }
}

// ---------------- launch ----------------

extern "C" void kernel_launch(void* const* d_in, const int* in_sizes, int n_in,
                              void* d_out, int out_size, void* d_ws, size_t ws_size,
                              hipStream_t stream) {
    const float* vf    = (const float*)d_in[0];
    const float* tf    = (const float*)d_in[1];
    const float* fc1w  = (const float*)d_in[2];
    const float* fc1b  = (const float*)d_in[3];
    const float* fc2w  = (const float*)d_in[4];
    const float* fc2b  = (const float*)d_in[5];
    const float* reluw = (const float*)d_in[6];
    const float* relub = (const float*)d_in[7];
    const float* w1rel = (const float*)d_in[8];
    const float* w1root= (const float*)d_in[9];
    const float* b1    = (const float*)d_in[10];
    const float* w2rel = (const float*)d_in[11];
    const float* w2root= (const float*)d_in[12];
    const float* b2    = (const float*)d_in[13];
    const float* fc3w  = (const float*)d_in[14];
    const float* fc3b  = (const float*)d_in[15];
    const int* ei      = (const int*)d_in[16];
    const int* et      = (const int*)d_in[17];
    const int* idx     = (const int*)d_in[18];
    float* out = (float*)d_out;

    char* W = (char*)d_ws;
    const size_t OFF_WTIN  = 0;
    const size_t OFF_WT1   = 204800;
    const size_t OFF_WT2   = 335872;
    const size_t OFF_BCOMB = 466944;
    const size_t OFF_DEGN  = 467456;
    const size_t OFF_CUR   = 667456;
    const size_t OFF_DEGR  = 867456;
    const size_t OFF_CNT   = 1467456;
    const size_t OFF_BASE  = 1467712;
    const size_t OFF_NORM  = 1667712;
    const size_t OFF_ELIST = 2267712;
    const size_t OFF_A     = 4667712;
    const size_t OFF_H0    = 43067712;
    const size_t OFF_H1    = 55867712;
    const size_t OFF_H2    = 68667712;
    const size_t OFF_VFPAD = 81467712;

    u16* WTin   = (u16*)(W + OFF_WTIN);
    u16* WT1    = (u16*)(W + OFF_WT1);
    u16* WT2    = (u16*)(W + OFF_WT2);
    float* bcomb= (float*)(W + OFF_BCOMB);
    int* degn   = (int*)(W + OFF_DEGN);
    int* cur    = (int*)(W + OFF_CUR);
    int* degr   = (int*)(W + OFF_DEGR);
    int* cnt    = (int*)(W + OFF_CNT);
    int* base   = (int*)(W + OFF_BASE);
    float* normf= (float*)(W + OFF_NORM);
    int* elist  = (int*)(W + OFF_ELIST);
    u16* Abuf   = (u16*)(W + OFF_A);
    u16* h0     = (u16*)(W + OFF_H0);
    u16* h1     = (u16*)(W + OFF_H1);
    u16* h2     = (u16*)(W + OFF_H2);
    float* vfp  = (float*)(W + OFF_VFPAD);

    const int GRID_GEMM = (NN + 63) / 64;   // 782 blocks -> ~3 blocks/CU co-resident

    k_zero<<<(250001 + 255) / 256, 256, 0, stream>>>(degn, 250001);
    k_padvf<<<(NN * 32 + 255) / 256, 256, 0, stream>>>(vf, vfp);

    k_win<<<800, 128, 0, stream>>>(fc1w, fc2w, reluw, WTin);
    k_bcomb<<<1, 128, 0, stream>>>(fc1b, fc2b, relub, reluw, bcomb);
    k_wrg<<<512, 128, 0, stream>>>(w1rel, w1root, WT1);
    k_wrg<<<512, 128, 0, stream>>>(w2rel, w2root, WT2);

    k_gemm_in<<<GRID_GEMM, 256, 0, stream>>>(tf, 768, vfp, 32, WTin, 800, bcomb, h0, NN);

    k_hist<<<(NE + 255) / 256, 256, 0, stream>>>(ei, et, degn, degr);
    k_alloc<<<(NN + 255) / 256, 256, 0, stream>>>(degn, base, cnt);
    k_norm<<<(3 * NN + 255) / 256, 256, 0, stream>>>(degr, normf);
    k_fill<<<(NE + 255) / 256, 256, 0, stream>>>(ei, et, base, cur, elist);

    k_agg<<<NN, 64, 0, stream>>>(h0, Abuf, elist, base, degn, normf);
    k_gemm_r1<<<GRID_GEMM, 256, 0, stream>>>(Abuf, 384, h0, 128, WT1, 512, b1, h1, NN);

    k_agg<<<NN, 64, 0, stream>>>(h1, Abuf, elist, base, degn, normf);
    k_gemm_r2<<<GRID_GEMM, 256, 0, stream>>>(Abuf, 384, h1, 128, WT2, 512, b2, h2, NN);

    k_out<<<(10000 + 3) / 4, 256, 0, stream>>>(h2, idx, fc3w, fc3b, out, 10000);
}